// Round 7
// baseline (161.115 us; speedup 1.0000x reference)
//
#include <hip/hip_runtime.h>
#include <stdint.h>

// DepthAwareConv2d: out = conv2d(x * depth, weight, pad=1) + bias
// (depth is channel-independent, so the depth-modulated im2col GEMM factors
//  into a plain 3x3 conv of xd = x*depth).
//
// R13 = (R7 prep) + (R12 conv) + B-register double-buffer.
//  - Prep: R7's half-row version (1024 row blocks, b128 LDS reads + dwordx4
//    stores). R1 (R7prep) was 4us faster e2e than R3/R6 (R6prep) at equal
//    conv time - the R2 regression was the conv wave-split, not this prep.
//  - Conv: R12 structure (XCD swizzle over flat 512 grid, FETCH 15.5MB,
//    conflicts 0) + breg[2][8] ping-pong: tap t prefetches tap t+1's B
//    fragments from LDS before t's MFMA cluster, so the ~220cy ds_read
//    latency hides under the previous tap's MFMAs instead of stalling
//    every tap (compiler wasn't pipelining: VGPR_Count was only 128).
//    Cross-phase prefetch happens after the barrier (staging race), one
//    small bubble per cc-phase (4 total).

#define C_IN 128
#define O_OUT 256
#define HW 128
#define NB 4
#define PADW 130

#define XD_ELEMS ((size_t)NB * PADW * PADW * C_IN)
#define XD_BYTES (XD_ELEMS * 2)          // 17,305,600 B
#define WT_ELEMS ((size_t)O_OUT * C_IN * 9)
#define WT_BYTES (WT_ELEMS * 2)          // 589,824 B

typedef __attribute__((ext_vector_type(8))) short short8;  // 8 bf16 (4 VGPRs)
typedef __attribute__((ext_vector_type(4))) float f32x4;
typedef __attribute__((ext_vector_type(2))) float f32x2;
typedef __attribute__((ext_vector_type(4))) unsigned uint4v;

__device__ __forceinline__ unsigned f2bf_bits(float f) {
  unsigned u = __builtin_bit_cast(unsigned, f);
  return (u + 0x7fffu + ((u >> 16) & 1u)) >> 16;   // RNE, inputs finite
}

__device__ __forceinline__ void async_load16(const void* g, void* l) {
  __builtin_amdgcn_global_load_lds(
      (__attribute__((address_space(1))) void*)g,
      (__attribute__((address_space(3))) void*)l, 16, 0, 0);
}

// ---- prep (single dispatch): xd rows + halo + weight frag-relayout ---------
// Blocks 0..1023  : one (n,y,h) half-row (64 channels). Phase 1: f32x2 reads
//                   of x (2 channels/iter), scale by depth, dword scatter to
//                   LDS output layout; phase 2: b128 reads + dwordx4 stores.
// Blocks 1024..1027: zero halo rows 0 and 129 of image n.
// Blocks 1028..1091: wt2 in MFMA-A-fragment order, contiguous per (s,wm,t):
//   gid = o0*147456 + s*4096 + wm*2048 + t*512 + lane*8 + j   (shorts)
//   o = o0*128 + wm*64 + t*16 + (lane&15)
//   cc = s/9; tap = s%9; c = cc*32 + (lane>>4)*8 + j
__global__ __launch_bounds__(256) void prep_all(const float* __restrict__ x,
                                                const float* __restrict__ depth,
                                                const float* __restrict__ w,
                                                short* __restrict__ xd,
                                                short* __restrict__ wt2) {
  const int R = blockIdx.x;
  const int tid = threadIdx.x;

  if (R >= NB * HW * 2 + NB) {              // ---- weight blocks
    int gid = (R - (NB * HW * 2 + NB)) * 4608 + tid;   // 64 * 4608 = 294912
#pragma unroll
    for (int i = 0; i < 18; ++i, gid += 256) {
      const int j = gid & 7;
      const int lane = (gid >> 3) & 63;
      const int t = (gid >> 9) & 3;
      const int wm = (gid >> 11) & 1;
      const int g2 = gid >> 12;
      const int s = g2 % 36;               // K-slot in conv order: cc*9 + tap
      const int o0 = g2 / 36;
      const int ln = lane & 15, q = lane >> 4;
      const int o = (o0 << 7) + (wm << 6) + (t << 4) + ln;
      const int cc = s / 9;
      const int tap = s % 9;
      const int c = (cc << 5) + (q << 3) + j;
      wt2[gid] = (short)f2bf_bits(w[((size_t)o * C_IN + c) * 9 + tap]);
    }
    return;
  }

  if (R >= NB * HW * 2) {                   // ---- halo-row zero blocks
    const int n = R - NB * HW * 2;
    uint4v* base0 = (uint4v*)(xd + (size_t)n * PADW * PADW * C_IN);
    uint4v* base1 = (uint4v*)(xd + ((size_t)n * PADW + (PADW - 1)) * PADW * C_IN);
    const uint4v z = {0u, 0u, 0u, 0u};
    const int per_row = PADW * C_IN * 2 / 16;   // 2080 uint4 per padded row
    for (int i = tid; i < per_row; i += 256) {
      base0[i] = z;
      base1[i] = z;
    }
    return;
  }

  // ---- half-row transform blocks: channels h*64..h*64+63 of row (n,y)
  // LDS layout: s32[px 0..127][36 dwords] (stride 36 keeps b128 16B-aligned;
  // cp slot 0..31 = channel pair within the 64-ch half).
  __shared__ __align__(16) unsigned s32[HW * 36];   // 18,432 B

  const int n = R >> 8;
  const int y = (R >> 1) & 127;
  const int h = R & 1;
  const int lane = tid & 63;
  const int wave = tid >> 6;

  // zero this half's 32 dwords of the two edge pixels (x=0 and x=129)
  {
    unsigned* row = (unsigned*)(xd + (size_t)(n * PADW + y + 1) * PADW * C_IN);
    if (tid < 32) row[(h << 5) + tid] = 0u;
    else if (tid < 64) row[(size_t)(PADW - 1) * 64 + (h << 5) + (tid - 32)] = 0u;
  }

  // phase 1: read 2 channels per iter (f32x2, coalesced), scale by depth,
  // scatter channel-pair dwords into LDS output layout.
  const f32x2 d2 = *(const f32x2*)(depth + ((size_t)n * HW + y) * HW + 2 * lane);
  const float* xrow =
      x + (((size_t)(n * C_IN + (h << 6)) * HW) + y) * HW + 2 * lane;
#pragma unroll
  for (int it = 0; it < 8; ++it) {
    const int cp = (wave << 3) + it;        // 0..31
    const f32x2 va = *(const f32x2*)(xrow + (size_t)(2 * cp) * HW * HW);
    const f32x2 vb = *(const f32x2*)(xrow + (size_t)(2 * cp + 1) * HW * HW);
    s32[(2 * lane) * 36 + cp] =
        f2bf_bits(va.x * d2.x) | (f2bf_bits(vb.x * d2.x) << 16);
    s32[(2 * lane + 1) * 36 + cp] =
        f2bf_bits(va.y * d2.y) | (f2bf_bits(vb.y * d2.y) << 16);
  }
  __syncthreads();

  // phase 2: b128 reads + dwordx4 stores (pixels 1..128, this channel half)
  unsigned* orow = (unsigned*)(xd + ((size_t)(n * PADW + y + 1) * PADW + 1) * C_IN);
#pragma unroll
  for (int i = 0; i < 4; ++i) {
    const int flat = tid + (i << 8);        // 0..1023
    const int px = flat >> 3, jj = flat & 7;
    const uint4v v = *(const uint4v*)&s32[px * 36 + (jj << 2)];
    *(uint4v*)&orow[(size_t)px * 64 + (h << 5) + (jj << 2)] = v;
  }
}

// ---- main MFMA implicit-GEMM conv ------------------------------------------
// Block: 256 threads (4 waves, 2x2), tile 128(o) x 256(px = 2 output rows).
// Wave tile 64(o) x 128(px): acc 4x8. K = 1152 as (cc 0..3) x (tap 0..8).
// Flat 512-block grid, XCD swizzle: swz = (bid&7)*64 + (bid>>3).
// Double-buffered LDS strips (stage spread over taps, after loadA) AND
// double-buffered B registers: tap t prefetches tap t+1's 8 fragments from
// LDS before t's MFMAs, hiding ds_read latency under the MFMA cluster.
// Cross-phase B-prefetch happens after the barrier (stage race).
__global__ __launch_bounds__(256, 2) void conv_mfma(
    const short* __restrict__ xd, const short* __restrict__ wt2,
    const float* __restrict__ bias, float* __restrict__ out) {
  __shared__ __align__(16) short xbuf[2][16640];   // 2 x [px_strip 520][32 ch]

  const int tid = threadIdx.x;
  const int swz = ((blockIdx.x & 7) << 6) + (blockIdx.x >> 3);  // 0..511
  const int o0b = swz & 1;              // o tile (x128)
  const int bx = swz >> 1;              // n*64 + ypair, 0..255
  const int n = bx >> 6;
  const int y = (bx & 63) << 1;         // first of two output rows
  const int lane = tid & 63;
  const int wave = tid >> 6;
  const int wm = wave & 1, wn = wave >> 1;
  const int ln = lane & 15, q = lane >> 4;

  // W fragment stream base (shorts): frag (s, wm*4+t) contiguous 1KB
  const short* wbase = wt2 + (size_t)o0b * 147456 + (wm << 11) + (lane << 3);

  // X strip staging: LDS chunk c = tid + j*256 (linear), global source chunk
  // pre-swizzled: q_src = (tid&3) ^ ((tid>>3)&3).
  const short* xsrc0 = xd + (size_t)(n * PADW + y) * PADW * C_IN +
                       (tid >> 2) * C_IN + ((tid & 3) ^ ((tid >> 3) & 3)) * 8;

  f32x4 acc[4][8] = {};
  short8 areg[2][4];
  short8 breg[2][8];

  auto loadA = [&](int s, int p) {
#pragma unroll
    for (int t = 0; t < 4; ++t)
      areg[p][t] = *(const short8*)(wbase + (size_t)s * 4096 + t * 512);
  };
  // read the 8 B fragments of (buffer buf, tap = ti*3+tj) into breg[p]
  auto readB = [&](int buf, int ti, int tj, int p) {
    const int rbase = (wn + ti) * 130 + tj;
#pragma unroll
    for (int u = 0; u < 8; ++u) {
      const int px = rbase + (u << 4) + ln;
      const int qx = (q ^ ((px >> 1) & 3)) << 3;   // bank swizzle (q-field)
      breg[p][u] = *(const short8*)(&xbuf[buf][0] + px * 32 + qx);
    }
  };

  {  // prologue: stage strip cc=0 into buf0
    short* xdst = &xbuf[0][0] + tid * 8;
#pragma unroll
    for (int j = 0; j < 8; ++j)
      async_load16(xsrc0 + j * 8192, xdst + j * 2048);
    if (tid < 32) async_load16(xsrc0 + 8 * 8192, xdst + 8 * 2048);
  }
  loadA(0, 0);
  __syncthreads();   // buf0 ready
  readB(0, 0, 0, 0); // B for (cc=0, tap=0)

#pragma unroll
  for (int cc = 0; cc < 4; ++cc) {
#pragma unroll
    for (int tap = 0; tap < 9; ++tap) {
      const int s = cc * 9 + tap;
      if (s + 1 < 36) loadA(s + 1, (s + 1) & 1);   // prefetch next a-frags

      if (cc + 1 < 4) {   // spread next-strip staging across taps (after loadA!)
        const short* sp = xsrc0 + ((cc + 1) << 5);
        short* xdst = &xbuf[(cc + 1) & 1][0] + tid * 8;
        if (tap < 8) async_load16(sp + tap * 8192, xdst + tap * 2048);
        if (tap == 0 && tid < 32)
          async_load16(sp + 8 * 8192, xdst + 8 * 2048);  // tail 32 chunks
      }

      // prefetch next tap's B fragments (same LDS buffer) into the other
      // breg bank; the lgkm wait before this tap's MFMAs then covers reads
      // issued a full tap ago.
      if (tap < 8) readB(cc & 1, (tap + 1) / 3, (tap + 1) % 3, (tap + 1) & 1);

      __builtin_amdgcn_s_setprio(1);
#pragma unroll
      for (int t = 0; t < 4; ++t)
#pragma unroll
        for (int u = 0; u < 8; ++u)
          acc[t][u] = __builtin_amdgcn_mfma_f32_16x16x32_bf16(
              areg[s & 1][t], breg[tap & 1][u], acc[t][u], 0, 0, 0);
      __builtin_amdgcn_s_setprio(0);
    }
    if (cc + 1 < 4) {
      __syncthreads();                   // buf(cc+1) staged+drained
      readB((cc + 1) & 1, 0, 0, 0);      // B for (cc+1, tap=0)
    }
  }

  // epilogue: D layout col=lane&15 (pixel), row=q*4+r (o)
  const int yrow = y + wn;
#pragma unroll
  for (int t = 0; t < 4; ++t) {
    const int ob = (o0b << 7) + (wm << 6) + (t << 4) + (q << 2);
#pragma unroll
    for (int u = 0; u < 8; ++u) {
      const int xcol = (u << 4) + ln;           // 0..127
#pragma unroll
      for (int r = 0; r < 4; ++r) {
        const int o = ob + r;
        out[(((size_t)n * O_OUT + o) * HW + yrow) * HW + xcol] =
            acc[t][u][r] + bias[o];
      }
    }
  }
}

// ---- fallback (only if ws_size is too small): naive direct conv ------------
__global__ void conv_naive(const float* __restrict__ x,
                           const float* __restrict__ depth,
                           const float* __restrict__ w,
                           const float* __restrict__ bias,
                           float* __restrict__ out) {
  const int gid = blockIdx.x * 256 + threadIdx.x;
  if (gid >= NB * O_OUT * HW * HW) return;
  const int xc = gid & 127;
  const int y = (gid >> 7) & 127;
  const int o = (gid >> 14) & 255;
  const int n = gid >> 22;
  float s = bias[o];
  for (int c = 0; c < C_IN; ++c)
    for (int i = 0; i < 3; ++i) {
      const int yy = y + i - 1;
      if (yy < 0 || yy >= HW) continue;
      for (int j = 0; j < 3; ++j) {
        const int xx = xc + j - 1;
        if (xx < 0 || xx >= HW) continue;
        s += w[((o * C_IN + c) * 3 + i) * 3 + j] *
             x[(((size_t)n * C_IN + c) * HW + yy) * HW + xx] *
             depth[((size_t)n * HW + yy) * HW + xx];
      }
    }
  out[gid] = s;
}

extern "C" void kernel_launch(void* const* d_in, const int* in_sizes, int n_in,
                              void* d_out, int out_size, void* d_ws, size_t ws_size,
                              hipStream_t stream) {
  const float* x = (const float*)d_in[0];
  const float* depth = (const float*)d_in[1];
  // d_in[2] = camera_params (unused by reference)
  const float* weight = (const float*)d_in[3];
  const float* bias = (const float*)d_in[4];
  float* out = (float*)d_out;

  const size_t need = XD_BYTES + WT_BYTES;
  if (ws_size < need) {
    conv_naive<<<(NB * O_OUT * HW * HW + 255) / 256, 256, 0, stream>>>(
        x, depth, weight, bias, out);
    return;
  }

  short* xd = (short*)d_ws;
  short* wt2 = (short*)((char*)d_ws + XD_BYTES);

  prep_all<<<NB * HW * 2 + NB + 64, 256, 0, stream>>>(x, depth, weight, xd, wt2);
  conv_mfma<<<dim3(NB * HW), 256, 0, stream>>>(xd, wt2, bias, out);
}

// Round 8
// 131.640 us; speedup vs baseline: 1.2239x; 1.2239x over previous
//
#include <hip/hip_runtime.h>
#include <stdint.h>

// DepthAwareConv2d: out = conv2d(x * depth, weight, pad=1) + bias
// (depth is channel-independent, so the depth-modulated im2col GEMM factors
//  into a plain 3x3 conv of xd = x*depth).
//
// R14 = R12 conv (best measured: 41.6us, FETCH 15.5MB, conflicts 0)
//     + faster prep.
//  - R13 post-mortem: breg ping-pong pushed regs past the 256/wave budget
//    (acc128 + areg32 + breg64 + addr) -> scratch spills (FETCH 92MB,
//    WRITE 180MB). Reverted; conv is byte-identical to R12.
//  - Prep phase 1 now loads f32x2 over a PIXEL PAIR per thread (16x8B loads
//    instead of 32x4B), scales by depth, and writes both packed dwords to
//    LDS with a b128-compatible XOR swizzle cp' = cp ^ ((px>>1)&28):
//    conflict-free writes (lanes 0,4,8,.. hit banks cp^4k, all distinct)
//    AND phase-2 ds_read_b128 stays contiguous (key low 2 bits are 0).
//    Phase 2: b128 reads (swizzled) + dwordx4 NHWC stores, unchanged shape.

#define C_IN 128
#define O_OUT 256
#define HW 128
#define NB 4
#define PADW 130

#define XD_ELEMS ((size_t)NB * PADW * PADW * C_IN)
#define XD_BYTES (XD_ELEMS * 2)          // 17,305,600 B
#define WT_ELEMS ((size_t)O_OUT * C_IN * 9)
#define WT_BYTES (WT_ELEMS * 2)          // 589,824 B

typedef __attribute__((ext_vector_type(8))) short short8;  // 8 bf16 (4 VGPRs)
typedef __attribute__((ext_vector_type(4))) float f32x4;
typedef __attribute__((ext_vector_type(2))) float f32x2;
typedef __attribute__((ext_vector_type(4))) unsigned uint4v;

__device__ __forceinline__ unsigned f2bf_bits(float f) {
  unsigned u = __builtin_bit_cast(unsigned, f);
  return (u + 0x7fffu + ((u >> 16) & 1u)) >> 16;   // RNE, inputs finite
}

__device__ __forceinline__ void async_load16(const void* g, void* l) {
  __builtin_amdgcn_global_load_lds(
      (__attribute__((address_space(1))) void*)g,
      (__attribute__((address_space(3))) void*)l, 16, 0, 0);
}

// ---- prep (single dispatch): xd rows + halo + weight frag-relayout ---------
// Blocks 0..1023  : one (n,y,h) half-row (64 channels). Phase 1: f32x2 loads
//                   over a px pair, XOR-swizzled conflict-free LDS writes.
//                   Phase 2: b128 reads (same XOR) + dwordx4 NHWC stores.
// Blocks 1024..1027: zero halo rows 0 and 129 of image n.
// Blocks 1028..1091: wt2 in MFMA-A-fragment order, contiguous per (s,wm,t):
//   gid = o0*147456 + s*4096 + wm*2048 + t*512 + lane*8 + j   (shorts)
//   o = o0*128 + wm*64 + t*16 + (lane&15)
//   cc = s/9; tap = s%9; c = cc*32 + (lane>>4)*8 + j
__global__ __launch_bounds__(256) void prep_all(const float* __restrict__ x,
                                                const float* __restrict__ depth,
                                                const float* __restrict__ w,
                                                short* __restrict__ xd,
                                                short* __restrict__ wt2) {
  const int R = blockIdx.x;
  const int tid = threadIdx.x;

  if (R >= NB * HW * 2 + NB) {              // ---- weight blocks
    int gid = (R - (NB * HW * 2 + NB)) * 4608 + tid;   // 64 * 4608 = 294912
#pragma unroll
    for (int i = 0; i < 18; ++i, gid += 256) {
      const int j = gid & 7;
      const int lane = (gid >> 3) & 63;
      const int t = (gid >> 9) & 3;
      const int wm = (gid >> 11) & 1;
      const int g2 = gid >> 12;
      const int s = g2 % 36;               // K-slot in conv order: cc*9 + tap
      const int o0 = g2 / 36;
      const int ln = lane & 15, q = lane >> 4;
      const int o = (o0 << 7) + (wm << 6) + (t << 4) + ln;
      const int cc = s / 9;
      const int tap = s % 9;
      const int c = (cc << 5) + (q << 3) + j;
      wt2[gid] = (short)f2bf_bits(w[((size_t)o * C_IN + c) * 9 + tap]);
    }
    return;
  }

  if (R >= NB * HW * 2) {                   // ---- halo-row zero blocks
    const int n = R - NB * HW * 2;
    uint4v* base0 = (uint4v*)(xd + (size_t)n * PADW * PADW * C_IN);
    uint4v* base1 = (uint4v*)(xd + ((size_t)n * PADW + (PADW - 1)) * PADW * C_IN);
    const uint4v z = {0u, 0u, 0u, 0u};
    const int per_row = PADW * C_IN * 2 / 16;   // 2080 uint4 per padded row
    for (int i = tid; i < per_row; i += 256) {
      base0[i] = z;
      base1[i] = z;
    }
    return;
  }

  // ---- half-row transform blocks: channels h*64..h*64+63 of row (n,y)
  // LDS layout: s32[px 0..127][36 dwords], cp slot stored at cp^((px>>1)&28)
  // (key low bits 0 -> phase-2 b128 of 4 consecutive cp stays contiguous).
  __shared__ __align__(16) unsigned s32[HW * 36];   // 18,432 B

  const int n = R >> 8;
  const int y = (R >> 1) & 127;
  const int h = R & 1;
  const int lane = tid & 63;
  const int wave = tid >> 6;

  // zero this half's 32 dwords of the two edge pixels (x=0 and x=129)
  {
    unsigned* row = (unsigned*)(xd + (size_t)(n * PADW + y + 1) * PADW * C_IN);
    if (tid < 32) row[(h << 5) + tid] = 0u;
    else if (tid < 64) row[(size_t)(PADW - 1) * 64 + (h << 5) + (tid - 32)] = 0u;
  }

  // phase 1: thread covers channel pairs cp = 8*wave..8*wave+7 at the pixel
  // pair {2*lane, 2*lane+1}. f32x2 loads (8B, coalesced: lanes span 512B of
  // consecutive px); both packed dwords written at XOR-swizzled cp slots
  // (conflict-free: lanes 0,4,8,.. land in banks cp^4k, all distinct).
  const f32x2 d2 = *(const f32x2*)(depth + ((size_t)n * HW + y) * HW + 2 * lane);
  const float* xrow =
      x + (((size_t)(n * C_IN + (h << 6)) * HW) + y) * HW + 2 * lane;
  const int key = lane & 28;                // == ((px>>1)&28) for both px
#pragma unroll
  for (int it = 0; it < 8; ++it) {
    const int cp = (wave << 3) + it;        // 0..31
    const f32x2 va = *(const f32x2*)(xrow + (size_t)(2 * cp) * HW * HW);
    const f32x2 vb = *(const f32x2*)(xrow + (size_t)(2 * cp + 1) * HW * HW);
    const int cs = cp ^ key;
    s32[(2 * lane) * 36 + cs] =
        f2bf_bits(va.x * d2.x) | (f2bf_bits(vb.x * d2.x) << 16);
    s32[(2 * lane + 1) * 36 + cs] =
        f2bf_bits(va.y * d2.y) | (f2bf_bits(vb.y * d2.y) << 16);
  }
  __syncthreads();

  // phase 2: b128 reads (apply the same XOR; key&3==0 keeps quads intact)
  // + dwordx4 stores (pixels 1..128, this channel half)
  unsigned* orow = (unsigned*)(xd + ((size_t)(n * PADW + y + 1) * PADW + 1) * C_IN);
#pragma unroll
  for (int i = 0; i < 4; ++i) {
    const int flat = tid + (i << 8);        // 0..1023
    const int px = flat >> 3, jj = flat & 7;
    const int cs = (jj << 2) ^ ((px >> 1) & 28);
    const uint4v v = *(const uint4v*)&s32[px * 36 + cs];
    *(uint4v*)&orow[(size_t)px * 64 + (h << 5) + (jj << 2)] = v;
  }
}

// ---- main MFMA implicit-GEMM conv (byte-identical to R12) ------------------
// Block: 256 threads (4 waves, 2x2), tile 128(o) x 256(px = 2 output rows).
// Wave tile 64(o) x 128(px): acc 4x8. K = 1152 as (cc 0..3) x (tap 0..8).
// Double-buffered strips; next-phase global_load_lds chunks spread across
// taps AFTER each tap's a-prefetch. One barrier per phase boundary.
// Flat 512-block grid with XCD swizzle: swz = (bid&7)*64 + (bid>>3); each
// XCD owns 32 consecutive bx (xd slice ~2.1MB -> L2-resident) and the two
// o0b tiles of each bx are time-adjacent (second strip read is an L2 hit).
__global__ __launch_bounds__(256, 2) void conv_mfma(
    const short* __restrict__ xd, const short* __restrict__ wt2,
    const float* __restrict__ bias, float* __restrict__ out) {
  __shared__ __align__(16) short xbuf[2][16640];   // 2 x [px_strip 520][32 ch]

  const int tid = threadIdx.x;
  const int swz = ((blockIdx.x & 7) << 6) + (blockIdx.x >> 3);  // 0..511
  const int o0b = swz & 1;              // o tile (x128)
  const int bx = swz >> 1;              // n*64 + ypair, 0..255
  const int n = bx >> 6;
  const int y = (bx & 63) << 1;         // first of two output rows
  const int lane = tid & 63;
  const int wave = tid >> 6;
  const int wm = wave & 1, wn = wave >> 1;
  const int ln = lane & 15, q = lane >> 4;

  // W fragment stream base (shorts): frag (s, wm*4+t) contiguous 1KB
  const short* wbase = wt2 + (size_t)o0b * 147456 + (wm << 11) + (lane << 3);

  // X strip staging: LDS chunk c = tid + j*256 (linear), global source chunk
  // pre-swizzled: q_src = (tid&3) ^ ((tid>>3)&3).
  const short* xsrc0 = xd + (size_t)(n * PADW + y) * PADW * C_IN +
                       (tid >> 2) * C_IN + ((tid & 3) ^ ((tid >> 3) & 3)) * 8;

  f32x4 acc[4][8] = {};
  short8 areg[2][4];

  auto loadA = [&](int s, int p) {
#pragma unroll
    for (int t = 0; t < 4; ++t)
      areg[p][t] = *(const short8*)(wbase + (size_t)s * 4096 + t * 512);
  };

  {  // prologue: stage strip cc=0 into buf0
    short* xdst = &xbuf[0][0] + tid * 8;
#pragma unroll
    for (int j = 0; j < 8; ++j)
      async_load16(xsrc0 + j * 8192, xdst + j * 2048);
    if (tid < 32) async_load16(xsrc0 + 8 * 8192, xdst + 8 * 2048);
  }
  loadA(0, 0);
  __syncthreads();   // buf0 ready

#pragma unroll
  for (int cc = 0; cc < 4; ++cc) {
#pragma unroll
    for (int tap = 0; tap < 9; ++tap) {
      const int s = cc * 9 + tap;
      if (s + 1 < 36) loadA(s + 1, (s + 1) & 1);   // prefetch next a-frags

      if (cc + 1 < 4) {   // spread next-strip staging across taps (after loadA!)
        const short* sp = xsrc0 + ((cc + 1) << 5);
        short* xdst = &xbuf[(cc + 1) & 1][0] + tid * 8;
        if (tap < 8) async_load16(sp + tap * 8192, xdst + tap * 2048);
        if (tap == 0 && tid < 32)
          async_load16(sp + 8 * 8192, xdst + 8 * 2048);  // tail 32 chunks
      }

      const int ti = tap / 3, tj = tap % 3;        // static under unroll
      const int rbase = (wn + ti) * 130 + tj;      // strip row + col shift

      short8 b[8];
#pragma unroll
      for (int u = 0; u < 8; ++u) {
        const int px = rbase + (u << 4) + ln;
        const int qx = (q ^ ((px >> 1) & 3)) << 3; // bank swizzle (q-field)
        b[u] = *(const short8*)(&xbuf[cc & 1][0] + px * 32 + qx);
      }
      __builtin_amdgcn_s_setprio(1);
#pragma unroll
      for (int t = 0; t < 4; ++t)
#pragma unroll
        for (int u = 0; u < 8; ++u)
          acc[t][u] = __builtin_amdgcn_mfma_f32_16x16x32_bf16(
              areg[s & 1][t], b[u], acc[t][u], 0, 0, 0);
      __builtin_amdgcn_s_setprio(0);
    }
    if (cc + 1 < 4) __syncthreads();   // buf(cc+1) staged+drained; buf(cc) free
  }

  // epilogue: D layout col=lane&15 (pixel), row=q*4+r (o)
  const int yrow = y + wn;
#pragma unroll
  for (int t = 0; t < 4; ++t) {
    const int ob = (o0b << 7) + (wm << 6) + (t << 4) + (q << 2);
#pragma unroll
    for (int u = 0; u < 8; ++u) {
      const int xcol = (u << 4) + ln;           // 0..127
#pragma unroll
      for (int r = 0; r < 4; ++r) {
        const int o = ob + r;
        out[(((size_t)n * O_OUT + o) * HW + yrow) * HW + xcol] =
            acc[t][u][r] + bias[o];
      }
    }
  }
}

// ---- fallback (only if ws_size is too small): naive direct conv ------------
__global__ void conv_naive(const float* __restrict__ x,
                           const float* __restrict__ depth,
                           const float* __restrict__ w,
                           const float* __restrict__ bias,
                           float* __restrict__ out) {
  const int gid = blockIdx.x * 256 + threadIdx.x;
  if (gid >= NB * O_OUT * HW * HW) return;
  const int xc = gid & 127;
  const int y = (gid >> 7) & 127;
  const int o = (gid >> 14) & 255;
  const int n = gid >> 22;
  float s = bias[o];
  for (int c = 0; c < C_IN; ++c)
    for (int i = 0; i < 3; ++i) {
      const int yy = y + i - 1;
      if (yy < 0 || yy >= HW) continue;
      for (int j = 0; j < 3; ++j) {
        const int xx = xc + j - 1;
        if (xx < 0 || xx >= HW) continue;
        s += w[((o * C_IN + c) * 3 + i) * 3 + j] *
             x[(((size_t)n * C_IN + c) * HW + yy) * HW + xx] *
             depth[((size_t)n * HW + yy) * HW + xx];
      }
    }
  out[gid] = s;
}

extern "C" void kernel_launch(void* const* d_in, const int* in_sizes, int n_in,
                              void* d_out, int out_size, void* d_ws, size_t ws_size,
                              hipStream_t stream) {
  const float* x = (const float*)d_in[0];
  const float* depth = (const float*)d_in[1];
  // d_in[2] = camera_params (unused by reference)
  const float* weight = (const float*)d_in[3];
  const float* bias = (const float*)d_in[4];
  float* out = (float*)d_out;

  const size_t need = XD_BYTES + WT_BYTES;
  if (ws_size < need) {
    conv_naive<<<(NB * O_OUT * HW * HW + 255) / 256, 256, 0, stream>>>(
        x, depth, weight, bias, out);
    return;
  }

  short* xd = (short*)d_ws;
  short* wt2 = (short*)((char*)d_ws + XD_BYTES);

  prep_all<<<NB * HW * 2 + NB + 64, 256, 0, stream>>>(x, depth, weight, xd, wt2);
  conv_mfma<<<dim3(NB * HW), 256, 0, stream>>>(xd, wt2, bias, out);
}

// Round 9
// 130.678 us; speedup vs baseline: 1.2329x; 1.0074x over previous
//
#include <hip/hip_runtime.h>
#include <stdint.h>

// DepthAwareConv2d: out = conv2d(x * depth, weight, pad=1) + bias
// (depth is channel-independent, so the depth-modulated im2col GEMM factors
//  into a plain 3x3 conv of xd = x*depth).
//
// R15 = R14 + rolling-window B pipeline in the conv inner loop.
//  Diagnosis: conv pinned at 891 TF (36% plateau) with conflicts=0, FETCH
//  15.5MB, L2-resident staging -> the stall is the per-tap burst structure:
//  8 ds_read_b128 -> lgkmcnt(0) -> 32 MFMAs, all 8 waves/CU lockstepped, so
//  LDS bursts and MFMA bursts never overlap (matrix-pipe issue occupancy
//  ~11% despite MfmaUtil 33%). R13's breg[2][8] fix spilled (224+ regs).
//  Fix: 4-slot rolling B window (16 regs): each u-step issues ONE ds_read
//  (u+2 of this tap, or u0/u1 of the next tap) then 4 MFMAs on a fragment
//  read 2 steps (~150cy) earlier. Counted lgkm waits, no drains, ds latency
//  hides under MFMA issue. Slots (u+2)&3 are compile-time (no scratch).
//  acc128 + areg32 + b16 + addr ~200 regs < 256 at 2 waves/SIMD.
//  Prep + staging + swizzles byte-identical to R14.

#define C_IN 128
#define O_OUT 256
#define HW 128
#define NB 4
#define PADW 130

#define XD_ELEMS ((size_t)NB * PADW * PADW * C_IN)
#define XD_BYTES (XD_ELEMS * 2)          // 17,305,600 B
#define WT_ELEMS ((size_t)O_OUT * C_IN * 9)
#define WT_BYTES (WT_ELEMS * 2)          // 589,824 B

typedef __attribute__((ext_vector_type(8))) short short8;  // 8 bf16 (4 VGPRs)
typedef __attribute__((ext_vector_type(4))) float f32x4;
typedef __attribute__((ext_vector_type(2))) float f32x2;
typedef __attribute__((ext_vector_type(4))) unsigned uint4v;

__device__ __forceinline__ unsigned f2bf_bits(float f) {
  unsigned u = __builtin_bit_cast(unsigned, f);
  return (u + 0x7fffu + ((u >> 16) & 1u)) >> 16;   // RNE, inputs finite
}

__device__ __forceinline__ void async_load16(const void* g, void* l) {
  __builtin_amdgcn_global_load_lds(
      (__attribute__((address_space(1))) void*)g,
      (__attribute__((address_space(3))) void*)l, 16, 0, 0);
}

// ---- prep (single dispatch): xd rows + halo + weight frag-relayout ---------
// Blocks 0..1023  : one (n,y,h) half-row (64 channels). Phase 1: f32x2 loads
//                   over a px pair, XOR-swizzled conflict-free LDS writes.
//                   Phase 2: b128 reads (same XOR) + dwordx4 NHWC stores.
// Blocks 1024..1027: zero halo rows 0 and 129 of image n.
// Blocks 1028..1091: wt2 in MFMA-A-fragment order, contiguous per (s,wm,t):
//   gid = o0*147456 + s*4096 + wm*2048 + t*512 + lane*8 + j   (shorts)
//   o = o0*128 + wm*64 + t*16 + (lane&15)
//   cc = s/9; tap = s%9; c = cc*32 + (lane>>4)*8 + j
__global__ __launch_bounds__(256) void prep_all(const float* __restrict__ x,
                                                const float* __restrict__ depth,
                                                const float* __restrict__ w,
                                                short* __restrict__ xd,
                                                short* __restrict__ wt2) {
  const int R = blockIdx.x;
  const int tid = threadIdx.x;

  if (R >= NB * HW * 2 + NB) {              // ---- weight blocks
    int gid = (R - (NB * HW * 2 + NB)) * 4608 + tid;   // 64 * 4608 = 294912
#pragma unroll
    for (int i = 0; i < 18; ++i, gid += 256) {
      const int j = gid & 7;
      const int lane = (gid >> 3) & 63;
      const int t = (gid >> 9) & 3;
      const int wm = (gid >> 11) & 1;
      const int g2 = gid >> 12;
      const int s = g2 % 36;               // K-slot in conv order: cc*9 + tap
      const int o0 = g2 / 36;
      const int ln = lane & 15, q = lane >> 4;
      const int o = (o0 << 7) + (wm << 6) + (t << 4) + ln;
      const int cc = s / 9;
      const int tap = s % 9;
      const int c = (cc << 5) + (q << 3) + j;
      wt2[gid] = (short)f2bf_bits(w[((size_t)o * C_IN + c) * 9 + tap]);
    }
    return;
  }

  if (R >= NB * HW * 2) {                   // ---- halo-row zero blocks
    const int n = R - NB * HW * 2;
    uint4v* base0 = (uint4v*)(xd + (size_t)n * PADW * PADW * C_IN);
    uint4v* base1 = (uint4v*)(xd + ((size_t)n * PADW + (PADW - 1)) * PADW * C_IN);
    const uint4v z = {0u, 0u, 0u, 0u};
    const int per_row = PADW * C_IN * 2 / 16;   // 2080 uint4 per padded row
    for (int i = tid; i < per_row; i += 256) {
      base0[i] = z;
      base1[i] = z;
    }
    return;
  }

  // ---- half-row transform blocks: channels h*64..h*64+63 of row (n,y)
  // LDS layout: s32[px 0..127][36 dwords], cp slot stored at cp^((px>>1)&28)
  // (key low bits 0 -> phase-2 b128 of 4 consecutive cp stays contiguous).
  __shared__ __align__(16) unsigned s32[HW * 36];   // 18,432 B

  const int n = R >> 8;
  const int y = (R >> 1) & 127;
  const int h = R & 1;
  const int lane = tid & 63;
  const int wave = tid >> 6;

  // zero this half's 32 dwords of the two edge pixels (x=0 and x=129)
  {
    unsigned* row = (unsigned*)(xd + (size_t)(n * PADW + y + 1) * PADW * C_IN);
    if (tid < 32) row[(h << 5) + tid] = 0u;
    else if (tid < 64) row[(size_t)(PADW - 1) * 64 + (h << 5) + (tid - 32)] = 0u;
  }

  // phase 1: thread covers channel pairs cp = 8*wave..8*wave+7 at the pixel
  // pair {2*lane, 2*lane+1}. f32x2 loads (8B, coalesced); both packed dwords
  // written at XOR-swizzled cp slots (conflict-free).
  const f32x2 d2 = *(const f32x2*)(depth + ((size_t)n * HW + y) * HW + 2 * lane);
  const float* xrow =
      x + (((size_t)(n * C_IN + (h << 6)) * HW) + y) * HW + 2 * lane;
  const int key = lane & 28;                // == ((px>>1)&28) for both px
#pragma unroll
  for (int it = 0; it < 8; ++it) {
    const int cp = (wave << 3) + it;        // 0..31
    const f32x2 va = *(const f32x2*)(xrow + (size_t)(2 * cp) * HW * HW);
    const f32x2 vb = *(const f32x2*)(xrow + (size_t)(2 * cp + 1) * HW * HW);
    const int cs = cp ^ key;
    s32[(2 * lane) * 36 + cs] =
        f2bf_bits(va.x * d2.x) | (f2bf_bits(vb.x * d2.x) << 16);
    s32[(2 * lane + 1) * 36 + cs] =
        f2bf_bits(va.y * d2.y) | (f2bf_bits(vb.y * d2.y) << 16);
  }
  __syncthreads();

  // phase 2: b128 reads (apply the same XOR; key&3==0 keeps quads intact)
  // + dwordx4 stores (pixels 1..128, this channel half)
  unsigned* orow = (unsigned*)(xd + ((size_t)(n * PADW + y + 1) * PADW + 1) * C_IN);
#pragma unroll
  for (int i = 0; i < 4; ++i) {
    const int flat = tid + (i << 8);        // 0..1023
    const int px = flat >> 3, jj = flat & 7;
    const int cs = (jj << 2) ^ ((px >> 1) & 28);
    const uint4v v = *(const uint4v*)&s32[px * 36 + cs];
    *(uint4v*)&orow[(size_t)px * 64 + (h << 5) + (jj << 2)] = v;
  }
}

// ---- main MFMA implicit-GEMM conv ------------------------------------------
// Block: 256 threads (4 waves, 2x2), tile 128(o) x 256(px = 2 output rows).
// Wave tile 64(o) x 128(px): acc 4x8. K = 1152 as (cc 0..3) x (tap 0..8).
// Double-buffered LDS strips; stage chunks spread across taps after loadA.
// Flat 512-block grid with XCD swizzle (xd slice L2-resident per XCD).
// NEW: rolling 4-slot B window. Per u-step: issue one ds_read (u+2 of this
// tap, or u0/u1 of the NEXT tap when u>=6), then 4 MFMAs on b[u&3], which
// was read 2 u-steps (~150cy of MFMA issue) earlier. Counted lgkm waits
// replace per-tap lgkmcnt(0) drains; LDS and MFMA pipes stay co-busy.
__global__ __launch_bounds__(256, 2) void conv_mfma(
    const short* __restrict__ xd, const short* __restrict__ wt2,
    const float* __restrict__ bias, float* __restrict__ out) {
  __shared__ __align__(16) short xbuf[2][16640];   // 2 x [px_strip 520][32 ch]

  const int tid = threadIdx.x;
  const int swz = ((blockIdx.x & 7) << 6) + (blockIdx.x >> 3);  // 0..511
  const int o0b = swz & 1;              // o tile (x128)
  const int bx = swz >> 1;              // n*64 + ypair, 0..255
  const int n = bx >> 6;
  const int y = (bx & 63) << 1;         // first of two output rows
  const int lane = tid & 63;
  const int wave = tid >> 6;
  const int wm = wave & 1, wn = wave >> 1;
  const int ln = lane & 15, q = lane >> 4;

  // W fragment stream base (shorts): frag (s, wm*4+t) contiguous 1KB
  const short* wbase = wt2 + (size_t)o0b * 147456 + (wm << 11) + (lane << 3);

  // X strip staging: LDS chunk c = tid + j*256 (linear), global source chunk
  // pre-swizzled: q_src = (tid&3) ^ ((tid>>3)&3).
  const short* xsrc0 = xd + (size_t)(n * PADW + y) * PADW * C_IN +
                       (tid >> 2) * C_IN + ((tid & 3) ^ ((tid >> 3) & 3)) * 8;

  f32x4 acc[4][8] = {};
  short8 areg[2][4];
  short8 b[4];        // rolling window; slots indexed by compile-time (u&3)

  auto loadA = [&](int s, int p) {
#pragma unroll
    for (int t = 0; t < 4; ++t)
      areg[p][t] = *(const short8*)(wbase + (size_t)s * 4096 + t * 512);
  };
  // read B fragment u of (buffer buf, tap ti*3+tj) into slot
  auto readB = [&](int buf, int ti, int tj, int u, int slot) {
    const int px = (wn + ti) * 130 + tj + (u << 4) + ln;
    const int qx = (q ^ ((px >> 1) & 3)) << 3;     // bank swizzle (q-field)
    b[slot] = *(const short8*)(&xbuf[buf][0] + px * 32 + qx);
  };

  {  // prologue: stage strip cc=0 into buf0
    short* xdst = &xbuf[0][0] + tid * 8;
#pragma unroll
    for (int j = 0; j < 8; ++j)
      async_load16(xsrc0 + j * 8192, xdst + j * 2048);
    if (tid < 32) async_load16(xsrc0 + 8 * 8192, xdst + 8 * 2048);
  }
  loadA(0, 0);
  __syncthreads();     // buf0 ready
  readB(0, 0, 0, 0, 0);  // (cc=0, tap=0) u=0
  readB(0, 0, 0, 1, 1);  // (cc=0, tap=0) u=1

#pragma unroll
  for (int cc = 0; cc < 4; ++cc) {
#pragma unroll
    for (int tap = 0; tap < 9; ++tap) {
      const int s = cc * 9 + tap;
      if (s + 1 < 36) loadA(s + 1, (s + 1) & 1);   // prefetch next a-frags

      if (cc + 1 < 4) {   // spread next-strip staging across taps (after loadA!)
        const short* sp = xsrc0 + ((cc + 1) << 5);
        short* xdst = &xbuf[(cc + 1) & 1][0] + tid * 8;
        if (tap < 8) async_load16(sp + tap * 8192, xdst + tap * 2048);
        if (tap == 0 && tid < 32)
          async_load16(sp + 8 * 8192, xdst + 8 * 2048);  // tail 32 chunks
      }

      const int ti = tap / 3, tj = tap % 3;              // static under unroll
      const int ti1 = (tap + 1) / 3, tj1 = (tap + 1) % 3;

      __builtin_amdgcn_s_setprio(1);
#pragma unroll
      for (int u = 0; u < 8; ++u) {
        // keep the window 2 fragments ahead
        if (u < 6)
          readB(cc & 1, ti, tj, u + 2, (u + 2) & 3);
        else if (tap < 8)
          readB(cc & 1, ti1, tj1, u - 6, (u + 2) & 3);   // next tap u0/u1
        // (tap==8: cross-phase refill happens after the barrier)
#pragma unroll
        for (int t = 0; t < 4; ++t)
          acc[t][u] = __builtin_amdgcn_mfma_f32_16x16x32_bf16(
              areg[s & 1][t], b[u & 3], acc[t][u], 0, 0, 0);
      }
      __builtin_amdgcn_s_setprio(0);
    }
    if (cc + 1 < 4) {
      __syncthreads();   // buf(cc+1) staged+drained; buf(cc) free
      readB((cc + 1) & 1, 0, 0, 0, 0);   // refill window: next phase tap0 u0/u1
      readB((cc + 1) & 1, 0, 0, 1, 1);
    }
  }

  // epilogue: D layout col=lane&15 (pixel), row=q*4+r (o)
  const int yrow = y + wn;
#pragma unroll
  for (int t = 0; t < 4; ++t) {
    const int ob = (o0b << 7) + (wm << 6) + (t << 4) + (q << 2);
#pragma unroll
    for (int u = 0; u < 8; ++u) {
      const int xcol = (u << 4) + ln;           // 0..127
#pragma unroll
      for (int r = 0; r < 4; ++r) {
        const int o = ob + r;
        out[(((size_t)n * O_OUT + o) * HW + yrow) * HW + xcol] =
            acc[t][u][r] + bias[o];
      }
    }
  }
}

// ---- fallback (only if ws_size is too small): naive direct conv ------------
__global__ void conv_naive(const float* __restrict__ x,
                           const float* __restrict__ depth,
                           const float* __restrict__ w,
                           const float* __restrict__ bias,
                           float* __restrict__ out) {
  const int gid = blockIdx.x * 256 + threadIdx.x;
  if (gid >= NB * O_OUT * HW * HW) return;
  const int xc = gid & 127;
  const int y = (gid >> 7) & 127;
  const int o = (gid >> 14) & 255;
  const int n = gid >> 22;
  float s = bias[o];
  for (int c = 0; c < C_IN; ++c)
    for (int i = 0; i < 3; ++i) {
      const int yy = y + i - 1;
      if (yy < 0 || yy >= HW) continue;
      for (int j = 0; j < 3; ++j) {
        const int xx = xc + j - 1;
        if (xx < 0 || xx >= HW) continue;
        s += w[((o * C_IN + c) * 3 + i) * 3 + j] *
             x[(((size_t)n * C_IN + c) * HW + yy) * HW + xx] *
             depth[((size_t)n * HW + yy) * HW + xx];
      }
    }
  out[gid] = s;
}

extern "C" void kernel_launch(void* const* d_in, const int* in_sizes, int n_in,
                              void* d_out, int out_size, void* d_ws, size_t ws_size,
                              hipStream_t stream) {
  const float* x = (const float*)d_in[0];
  const float* depth = (const float*)d_in[1];
  // d_in[2] = camera_params (unused by reference)
  const float* weight = (const float*)d_in[3];
  const float* bias = (const float*)d_in[4];
  float* out = (float*)d_out;

  const size_t need = XD_BYTES + WT_BYTES;
  if (ws_size < need) {
    conv_naive<<<(NB * O_OUT * HW * HW + 255) / 256, 256, 0, stream>>>(
        x, depth, weight, bias, out);
    return;
  }

  short* xd = (short*)d_ws;
  short* wt2 = (short*)((char*)d_ws + XD_BYTES);

  prep_all<<<NB * HW * 2 + NB + 64, 256, 0, stream>>>(x, depth, weight, xd, wt2);
  conv_mfma<<<dim3(NB * HW), 256, 0, stream>>>(xd, wt2, bias, out);
}